// Round 1
// baseline (657.204 us; speedup 1.0000x reference)
//
#include <hip/hip_runtime.h>
#include <hip/hip_bf16.h>

// Problem constants
#define Bb 2
#define Ss 2048
#define Ee 2048
#define Hh 16
#define Dd 128
#define Mrows (Bb*Ss)   // 4096

typedef short short8 __attribute__((ext_vector_type(8)));
typedef float f32x4 __attribute__((ext_vector_type(4)));

__device__ __forceinline__ unsigned short bf_rne(float f) {
    unsigned u = __builtin_bit_cast(unsigned, f);
    u += 0x7fffu + ((u >> 16) & 1u);
    return (unsigned short)(u >> 16);
}
__device__ __forceinline__ float bf2f(unsigned short x) {
    unsigned u = ((unsigned)x) << 16;
    return __builtin_bit_cast(float, u);
}
__device__ __forceinline__ void load_lds16(const void* g, void* l) {
    __builtin_amdgcn_global_load_lds(
        (const __attribute__((address_space(1))) unsigned int*)g,
        (__attribute__((address_space(3))) unsigned int*)l, 16, 0, 0);
}

// ---------------- fp32 -> bf16 cast (x4 vectorized) ----------------
__global__ void cast4_kernel(const float4* __restrict__ in, ushort4* __restrict__ out, int n4) {
    int i = blockIdx.x * 256 + threadIdx.x;
    if (i < n4) {
        float4 v = in[i];
        ushort4 o;
        o.x = bf_rne(v.x); o.y = bf_rne(v.y); o.z = bf_rne(v.z); o.w = bf_rne(v.w);
        out[i] = o;
    }
}

// ---------------- GEMM: C[m,n] = sum_k A[m,k]*W[n,k] + bias[n] ----------------
// A: [M][K] bf16 row-major; W: [N][K] bf16 row-major (i.e. x @ w.T).
// mode 0: write fp32 C[m*N+n].  mode 1: write bf16 to [B,H,S,D] (m=b*S+s, n=h*D+d).
__global__ __launch_bounds__(256) void gemm_bt(
    const short* __restrict__ A, const short* __restrict__ W,
    const float* __restrict__ bias, float* __restrict__ Cf, short* __restrict__ Cb,
    int M, int N, int K, int mode)
{
    __shared__ short As[128*32];
    __shared__ short Bs[128*32];
    const int tid  = threadIdx.x;
    const int wave = tid >> 6;
    const int lane = tid & 63;
    const int quad = lane >> 4;
    const int l16  = lane & 15;
    const int m0 = blockIdx.x * 128;
    const int n0 = blockIdx.y * 128;
    const int wm = (wave & 1) * 64;
    const int wn = (wave >> 1) * 64;

    f32x4 acc[4][4] = {};

    // staging: wave stages rows [wave*32, wave*32+32): lane i -> row +i/4, col (i%4)*8 shorts
    const int srow = wave * 32 + (lane >> 2);
    const int scol = (lane & 3) * 8;
    const size_t a_base = (size_t)(m0 + srow) * K + scol;
    const size_t b_base = (size_t)(n0 + srow) * K + scol;

    for (int kt = 0; kt < K; kt += 32) {
        __syncthreads();
        // stage A tile rows [wave*32, wave*32+32)
        load_lds16(A + a_base + kt,                 &As[(wave*32) * 32]);
        load_lds16(A + a_base + (size_t)16*K + kt,  &As[(wave*32 + 16) * 32]);
        load_lds16(W + b_base + kt,                 &Bs[(wave*32) * 32]);
        load_lds16(W + b_base + (size_t)16*K + kt,  &Bs[(wave*32 + 16) * 32]);
        __syncthreads();

        short8 af[4], bfr[4];
        #pragma unroll
        for (int i = 0; i < 4; ++i)
            af[i] = *(const short8*)&As[(wm + i*16 + l16)*32 + quad*8];
        #pragma unroll
        for (int j = 0; j < 4; ++j)
            bfr[j] = *(const short8*)&Bs[(wn + j*16 + l16)*32 + quad*8];
        #pragma unroll
        for (int i = 0; i < 4; ++i)
            #pragma unroll
            for (int j = 0; j < 4; ++j)
                acc[i][j] = __builtin_amdgcn_mfma_f32_16x16x32_bf16(af[i], bfr[j], acc[i][j], 0, 0, 0);
    }

    // epilogue: D row=(quad*4+r) [m-dim], col=l16 [n-dim]
    #pragma unroll
    for (int i = 0; i < 4; ++i) {
        #pragma unroll
        for (int j = 0; j < 4; ++j) {
            #pragma unroll
            for (int r = 0; r < 4; ++r) {
                int gm = m0 + wm + i*16 + quad*4 + r;
                int gn = n0 + wn + j*16 + l16;
                float v = acc[i][j][r] + bias[gn];
                if (mode == 0) {
                    Cf[(size_t)gm * N + gn] = v;
                } else {
                    int b = gm >> 11, s = gm & (Ss-1);
                    int h = gn >> 7,  d = gn & (Dd-1);
                    Cb[(((size_t)(b*Hh + h)) * Ss + s) * Dd + d] = (short)bf_rne(v);
                }
            }
        }
    }
}

// ---------------- RoPE in place on [B,H,S,D] bf16 (rotate-half), optional scale ----------------
__global__ void rope_kernel(short* __restrict__ X, const float* __restrict__ cosT,
                            const float* __restrict__ sinT, float scale) {
    int idx = blockIdx.x * 256 + threadIdx.x;   // B*H*S*64 threads
    int d  = idx & 63;
    int s  = (idx >> 6) & (Ss - 1);
    int bh = idx >> 17;
    size_t base = ((size_t)bh * Ss + s) * Dd;
    float x1 = bf2f((unsigned short)X[base + d]);
    float x2 = bf2f((unsigned short)X[base + d + 64]);
    float c  = cosT[s*Dd + d];
    float sn = sinT[s*Dd + d];
    float y1 = (x1 * c - x2 * sn) * scale;
    float y2 = (x2 * c + x1 * sn) * scale;
    X[base + d]      = (short)bf_rne(y1);
    X[base + d + 64] = (short)bf_rne(y2);
}

// ---------------- Flash attention (causal), bf16 MFMA ----------------
// Q,K,V: [B,H,S,D] bf16 (Q pre-scaled by 1/sqrt(D)).  O: [B,S,E] bf16.
// Block: 256 thr = 4 waves; Q-tile = 64 rows (wave w owns rows w*16..w*16+15); K-tile = 64.
__global__ __launch_bounds__(256) void attn_kernel(
    const short* __restrict__ Q, const short* __restrict__ Kk,
    const short* __restrict__ V, short* __restrict__ O)
{
    __shared__ short Ks[64 * 136];      // [kcol][d], stride 136 (pad)
    __shared__ short Vt[128 * 72];      // [d][kcol], stride 72 (pad)
    __shared__ short Pw[4][16 * 72];    // per-wave P [qrow][kcol], stride 72

    const int tid  = threadIdx.x;
    const int wave = tid >> 6;
    const int lane = tid & 63;
    const int quad = lane >> 4;
    const int l16  = lane & 15;
    const int qt = blockIdx.x;          // 0..31 (S/64)
    const int bh = blockIdx.y;          // 0..31 (B*H)
    const int b  = bh >> 4, h = bh & 15;
    const size_t head_off = (size_t)bh * Ss * Dd;

    // Q fragments (A-operand: m=l16, k=quad*8+j), kept in regs
    const int qrow = qt*64 + wave*16 + l16;
    short8 qf[4];
    #pragma unroll
    for (int ds = 0; ds < 4; ++ds)
        qf[ds] = *(const short8*)&Q[head_off + (size_t)qrow*Dd + ds*32 + quad*8];

    f32x4 o[8] = {};
    float m_i[4], l_i[4];
    #pragma unroll
    for (int r = 0; r < 4; ++r) { m_i[r] = -__builtin_inff(); l_i[r] = 0.f; }

    // staging assignments
    const int skc = tid >> 2, schunk = tid & 3;   // Ks: coalesced
    const int vkc = tid & 63, vpart = tid >> 6;   // Vt: conflict-free transpose writes

    const int ktiles = qt + 1;
    for (int kt = 0; kt < ktiles; ++kt) {
        const int k0 = kt * 64;
        __syncthreads();
        // stage K tile [64][128] -> Ks (row stride 136)
        {
            const short* g = &Kk[head_off + (size_t)(k0 + skc)*Dd + schunk*32];
            short* l = &Ks[skc*136 + schunk*32];
            #pragma unroll
            for (int i = 0; i < 4; ++i)
                *(short8*)(l + i*8) = *(const short8*)(g + i*8);
        }
        // stage V tile transposed -> Vt[d][kc] (row stride 72)
        {
            const short* g = &V[head_off + (size_t)(k0 + vkc)*Dd + vpart*32];
            #pragma unroll
            for (int i = 0; i < 4; ++i) {
                short8 v = *(const short8*)(g + i*8);
                #pragma unroll
                for (int j = 0; j < 8; ++j)
                    Vt[(vpart*32 + i*8 + j)*72 + vkc] = v[j];
            }
        }
        __syncthreads();

        // S = Q K^T  (B-operand from Ks: n=kcol=l16+jk*16, k=d)
        f32x4 sc[4] = {};
        #pragma unroll
        for (int jk = 0; jk < 4; ++jk)
            #pragma unroll
            for (int ds = 0; ds < 4; ++ds) {
                short8 kf = *(const short8*)&Ks[(jk*16 + l16)*136 + ds*32 + quad*8];
                sc[jk] = __builtin_amdgcn_mfma_f32_16x16x32_bf16(qf[ds], kf, sc[jk], 0, 0, 0);
            }

        // causal mask: row q = qt*64+wave*16+quad*4+r ; col k = k0+jk*16+l16
        const int qg = qt*64 + wave*16 + quad*4;
        #pragma unroll
        for (int jk = 0; jk < 4; ++jk) {
            int kg = k0 + jk*16 + l16;
            #pragma unroll
            for (int r = 0; r < 4; ++r)
                if (kg > qg + r) sc[jk][r] = -__builtin_inff();
        }

        // online softmax per q-row (rows live across 16 lanes of same quad)
        float alpha[4];
        #pragma unroll
        for (int r = 0; r < 4; ++r) {
            float m = fmaxf(fmaxf(sc[0][r], sc[1][r]), fmaxf(sc[2][r], sc[3][r]));
            #pragma unroll
            for (int off = 1; off < 16; off <<= 1)
                m = fmaxf(m, __shfl_xor(m, off));
            float mn = fmaxf(m_i[r], m);
            alpha[r] = __expf(m_i[r] - mn);
            m_i[r] = mn;
            float s = 0.f;
            #pragma unroll
            for (int jk = 0; jk < 4; ++jk) {
                float p = __expf(sc[jk][r] - mn);
                sc[jk][r] = p;
                s += p;
            }
            #pragma unroll
            for (int off = 1; off < 16; off <<= 1)
                s += __shfl_xor(s, off);
            l_i[r] = l_i[r] * alpha[r] + s;
        }

        // P (C/D layout) -> LDS -> A-operand layout
        #pragma unroll
        for (int jk = 0; jk < 4; ++jk)
            #pragma unroll
            for (int r = 0; r < 4; ++r)
                Pw[wave][(quad*4 + r)*72 + jk*16 + l16] = (short)bf_rne(sc[jk][r]);

        // rescale O accumulator
        #pragma unroll
        for (int dt = 0; dt < 8; ++dt)
            #pragma unroll
            for (int r = 0; r < 4; ++r)
                o[dt][r] *= alpha[r];

        short8 pa[2];
        pa[0] = *(const short8*)&Pw[wave][l16*72 + quad*8];
        pa[1] = *(const short8*)&Pw[wave][l16*72 + 32 + quad*8];
        #pragma unroll
        for (int dt = 0; dt < 8; ++dt)
            #pragma unroll
            for (int kk = 0; kk < 2; ++kk) {
                short8 vf = *(const short8*)&Vt[(dt*16 + l16)*72 + kk*32 + quad*8];
                o[dt] = __builtin_amdgcn_mfma_f32_16x16x32_bf16(pa[kk], vf, o[dt], 0, 0, 0);
            }
    }

    // epilogue: O[b, s=qrow, h*128 + d] = o / l
    #pragma unroll
    for (int r = 0; r < 4; ++r) {
        float inv = 1.0f / l_i[r];
        int srow = qt*64 + wave*16 + quad*4 + r;
        size_t obase = ((size_t)b * Ss + srow) * Ee + h * Dd;
        #pragma unroll
        for (int dt = 0; dt < 8; ++dt)
            O[obase + dt*16 + l16] = (short)bf_rne(o[dt][r] * inv);
    }
}

extern "C" void kernel_launch(void* const* d_in, const int* in_sizes, int n_in,
                              void* d_out, int out_size, void* d_ws, size_t ws_size,
                              hipStream_t stream) {
    const float* x_q  = (const float*)d_in[0];
    const float* x_kv = (const float*)d_in[1];
    const float* cosT = (const float*)d_in[2];
    const float* sinT = (const float*)d_in[3];
    const float* wq = (const float*)d_in[4];
    const float* bq = (const float*)d_in[5];
    const float* wk = (const float*)d_in[6];
    const float* bk = (const float*)d_in[7];
    const float* wv = (const float*)d_in[8];
    const float* bv = (const float*)d_in[9];
    const float* wo = (const float*)d_in[10];
    const float* bo = (const float*)d_in[11];

    // workspace carve-up
    size_t off = 0;
    auto alloc = [&](size_t bytes) {
        void* p = (char*)d_ws + off;
        off += (bytes + 255) & ~(size_t)255;
        return p;
    };
    const size_t nX = (size_t)Mrows * Ee;      // 8,388,608
    const size_t nW = (size_t)Ee * Ee;         // 4,194,304
    short* xq16  = (short*)alloc(nX * 2);
    short* xkv16 = (short*)alloc(nX * 2);
    short* wq16  = (short*)alloc(nW * 2);
    short* wk16  = (short*)alloc(nW * 2);
    short* wv16  = (short*)alloc(nW * 2);
    short* wo16  = (short*)alloc(nW * 2);
    short* Qr    = (short*)alloc(nX * 2);      // [B,H,S,D]
    short* Kr    = (short*)alloc(nX * 2);
    short* Vb    = (short*)alloc(nX * 2);
    short* Ob    = (short*)alloc(nX * 2);      // [B,S,E]

    // 1) casts
    cast4_kernel<<<(int)(nX/4 + 255)/256, 256, 0, stream>>>((const float4*)x_q,  (ushort4*)xq16,  (int)(nX/4));
    cast4_kernel<<<(int)(nX/4 + 255)/256, 256, 0, stream>>>((const float4*)x_kv, (ushort4*)xkv16, (int)(nX/4));
    cast4_kernel<<<(int)(nW/4 + 255)/256, 256, 0, stream>>>((const float4*)wq, (ushort4*)wq16, (int)(nW/4));
    cast4_kernel<<<(int)(nW/4 + 255)/256, 256, 0, stream>>>((const float4*)wk, (ushort4*)wk16, (int)(nW/4));
    cast4_kernel<<<(int)(nW/4 + 255)/256, 256, 0, stream>>>((const float4*)wv, (ushort4*)wv16, (int)(nW/4));
    cast4_kernel<<<(int)(nW/4 + 255)/256, 256, 0, stream>>>((const float4*)wo, (ushort4*)wo16, (int)(nW/4));

    // 2) QKV projections (write bf16 [B,H,S,D] with bias)
    dim3 ggrid(Mrows/128, Ee/128);
    gemm_bt<<<ggrid, 256, 0, stream>>>(xq16,  wq16, bq, nullptr, Qr, Mrows, Ee, Ee, 1);
    gemm_bt<<<ggrid, 256, 0, stream>>>(xkv16, wk16, bk, nullptr, Kr, Mrows, Ee, Ee, 1);
    gemm_bt<<<ggrid, 256, 0, stream>>>(xkv16, wv16, bv, nullptr, Vb, Mrows, Ee, Ee, 1);

    // 3) RoPE (Q gets 1/sqrt(D) folded in)
    int rope_blocks = (Bb*Hh*Ss*64) / 256;
    rope_kernel<<<rope_blocks, 256, 0, stream>>>(Qr, cosT, sinT, 0.08838834764831845f);
    rope_kernel<<<rope_blocks, 256, 0, stream>>>(Kr, cosT, sinT, 1.0f);

    // 4) causal flash attention -> Ob [B,S,E] bf16
    attn_kernel<<<dim3(Ss/64, Bb*Hh), 256, 0, stream>>>(Qr, Kr, Vb, Ob);

    // 5) output projection -> fp32 d_out
    gemm_bt<<<ggrid, 256, 0, stream>>>(Ob, wo16, bo, (float*)d_out, nullptr, Mrows, Ee, Ee, 0);
}

// Round 2
// 512.039 us; speedup vs baseline: 1.2835x; 1.2835x over previous
//
#include <hip/hip_runtime.h>
#include <hip/hip_bf16.h>

// Problem constants
#define Bb 2
#define Ss 2048
#define Ee 2048
#define Hh 16
#define Dd 128
#define Mrows (Bb*Ss)   // 4096

typedef short short8 __attribute__((ext_vector_type(8)));
typedef float f32x4 __attribute__((ext_vector_type(4)));

__device__ __forceinline__ unsigned short bf_rne(float f) {
    unsigned u = __builtin_bit_cast(unsigned, f);
    u += 0x7fffu + ((u >> 16) & 1u);
    return (unsigned short)(u >> 16);
}
__device__ __forceinline__ float bf2f(unsigned short x) {
    unsigned u = ((unsigned)x) << 16;
    return __builtin_bit_cast(float, u);
}
__device__ __forceinline__ void load_lds16(const void* g, void* l) {
    __builtin_amdgcn_global_load_lds(
        (const __attribute__((address_space(1))) unsigned int*)g,
        (__attribute__((address_space(3))) unsigned int*)l, 16, 0, 0);
}

// ---------------- fp32 -> bf16 cast (x4 vectorized) ----------------
__global__ void cast4_kernel(const float4* __restrict__ in, ushort4* __restrict__ out, int n4) {
    int i = blockIdx.x * 256 + threadIdx.x;
    if (i < n4) {
        float4 v = in[i];
        ushort4 o;
        o.x = bf_rne(v.x); o.y = bf_rne(v.y); o.z = bf_rne(v.z); o.w = bf_rne(v.w);
        out[i] = o;
    }
}

// ---------------- GEMM: C[m,n] = sum_k A[m,k]*W[n,k] + bias[n] ----------------
__global__ __launch_bounds__(256) void gemm_bt(
    const short* __restrict__ A, const short* __restrict__ W,
    const float* __restrict__ bias, float* __restrict__ Cf, short* __restrict__ Cb,
    int M, int N, int K, int mode)
{
    __shared__ short As[128*32];
    __shared__ short Bs[128*32];
    const int tid  = threadIdx.x;
    const int wave = tid >> 6;
    const int lane = tid & 63;
    const int quad = lane >> 4;
    const int l16  = lane & 15;
    const int m0 = blockIdx.x * 128;
    const int n0 = blockIdx.y * 128;
    const int wm = (wave & 1) * 64;
    const int wn = (wave >> 1) * 64;

    f32x4 acc[4][4] = {};

    const int srow = wave * 32 + (lane >> 2);
    const int scol = (lane & 3) * 8;
    const size_t a_base = (size_t)(m0 + srow) * K + scol;
    const size_t b_base = (size_t)(n0 + srow) * K + scol;

    for (int kt = 0; kt < K; kt += 32) {
        __syncthreads();
        load_lds16(A + a_base + kt,                 &As[(wave*32) * 32]);
        load_lds16(A + a_base + (size_t)16*K + kt,  &As[(wave*32 + 16) * 32]);
        load_lds16(W + b_base + kt,                 &Bs[(wave*32) * 32]);
        load_lds16(W + b_base + (size_t)16*K + kt,  &Bs[(wave*32 + 16) * 32]);
        __syncthreads();

        short8 af[4], bfr[4];
        #pragma unroll
        for (int i = 0; i < 4; ++i)
            af[i] = *(const short8*)&As[(wm + i*16 + l16)*32 + quad*8];
        #pragma unroll
        for (int j = 0; j < 4; ++j)
            bfr[j] = *(const short8*)&Bs[(wn + j*16 + l16)*32 + quad*8];
        #pragma unroll
        for (int i = 0; i < 4; ++i)
            #pragma unroll
            for (int j = 0; j < 4; ++j)
                acc[i][j] = __builtin_amdgcn_mfma_f32_16x16x32_bf16(af[i], bfr[j], acc[i][j], 0, 0, 0);
    }

    #pragma unroll
    for (int i = 0; i < 4; ++i) {
        #pragma unroll
        for (int j = 0; j < 4; ++j) {
            #pragma unroll
            for (int r = 0; r < 4; ++r) {
                int gm = m0 + wm + i*16 + quad*4 + r;
                int gn = n0 + wn + j*16 + l16;
                float v = acc[i][j][r] + bias[gn];
                if (mode == 0) {
                    Cf[(size_t)gm * N + gn] = v;
                } else {
                    int b = gm >> 11, s = gm & (Ss-1);
                    int h = gn >> 7,  d = gn & (Dd-1);
                    Cb[(((size_t)(b*Hh + h)) * Ss + s) * Dd + d] = (short)bf_rne(v);
                }
            }
        }
    }
}

// ---------------- RoPE in place on [B,H,S,D] bf16 ----------------
__global__ void rope_kernel(short* __restrict__ X, const float* __restrict__ cosT,
                            const float* __restrict__ sinT, float scale) {
    int idx = blockIdx.x * 256 + threadIdx.x;
    int d  = idx & 63;
    int s  = (idx >> 6) & (Ss - 1);
    int bh = idx >> 17;
    size_t base = ((size_t)bh * Ss + s) * Dd;
    float x1 = bf2f((unsigned short)X[base + d]);
    float x2 = bf2f((unsigned short)X[base + d + 64]);
    float c  = cosT[s*Dd + d];
    float sn = sinT[s*Dd + d];
    float y1 = (x1 * c - x2 * sn) * scale;
    float y2 = (x2 * c + x1 * sn) * scale;
    X[base + d]      = (short)bf_rne(y1);
    X[base + d + 64] = (short)bf_rne(y2);
}

// ---------------- Flash attention (causal), bf16 MFMA, load-balanced ----------------
// Grid: (16, B*H). Block i handles Q-tiles {i, 31-i} -> uniform 33 K-tile iters.
__global__ __launch_bounds__(256) void attn_kernel(
    const short* __restrict__ Q, const short* __restrict__ Kk,
    const short* __restrict__ V, short* __restrict__ O)
{
    __shared__ short Ks[64 * 136];      // [kcol][d], stride 136
    __shared__ short Vt[128 * 72];      // [d][kcol], stride 72
    __shared__ short Pw[4][16 * 72];    // per-wave P [qrow][kcol], stride 72

    const int tid  = threadIdx.x;
    const int wave = tid >> 6;
    const int lane = tid & 63;
    const int quad = lane >> 4;
    const int l16  = lane & 15;
    const int pairi = blockIdx.x;       // 0..15
    const int bh = blockIdx.y;          // 0..31
    const int b  = bh >> 4, h = bh & 15;
    const size_t head_off = (size_t)bh * Ss * Dd;
    const short* Kg = Kk + head_off;
    const short* Vg = V + head_off;

    // staging thread mappings
    const int skc = tid >> 2, schunk = tid & 3;   // K: row skc, 32-short chunk
    const int kpair = tid & 31, dgrp = tid >> 5;  // V: rows 2*kpair,+1 ; d 16-group

    for (int half = 0; half < 2; ++half) {
        const int qt = half ? (31 - pairi) : pairi;

        // Q fragments (A-operand), kept in regs
        const int qrow = qt*64 + wave*16 + l16;
        short8 qf[4];
        #pragma unroll
        for (int ds = 0; ds < 4; ++ds)
            qf[ds] = *(const short8*)&Q[head_off + (size_t)qrow*Dd + ds*32 + quad*8];

        f32x4 o[8] = {};
        float m_i[4], l_i[4];
        #pragma unroll
        for (int r = 0; r < 4; ++r) { m_i[r] = -__builtin_inff(); l_i[r] = 0.f; }

        // prefetch tile 0 into registers
        short8 kr[4], va[2], vb[2];
        {
            const short* g = &Kg[(size_t)skc * Dd + schunk*32];
            #pragma unroll
            for (int i = 0; i < 4; ++i) kr[i] = *(const short8*)(g + i*8);
            const short* gv = &Vg[(size_t)(2*kpair) * Dd + dgrp*16];
            #pragma unroll
            for (int c = 0; c < 2; ++c) { va[c] = *(const short8*)(gv + c*8); vb[c] = *(const short8*)(gv + Dd + c*8); }
        }

        for (int kt = 0; kt <= qt; ++kt) {
            __syncthreads();   // previous tile's consumers done
            // write staged regs -> LDS
            {
                short* l = &Ks[skc*136 + schunk*32];
                #pragma unroll
                for (int i = 0; i < 4; ++i) *(short8*)(l + i*8) = kr[i];
            }
            #pragma unroll
            for (int j = 0; j < 16; ++j) {
                unsigned lo = (unsigned short)va[j>>3][j&7];
                unsigned hi = (unsigned short)vb[j>>3][j&7];
                *(unsigned*)&Vt[(dgrp*16 + j)*72 + 2*kpair] = lo | (hi << 16);
            }
            // prefetch next tile (in flight during compute)
            if (kt < qt) {
                const int k0n = (kt+1)*64;
                const short* g = &Kg[(size_t)(k0n + skc) * Dd + schunk*32];
                #pragma unroll
                for (int i = 0; i < 4; ++i) kr[i] = *(const short8*)(g + i*8);
                const short* gv = &Vg[(size_t)(k0n + 2*kpair) * Dd + dgrp*16];
                #pragma unroll
                for (int c = 0; c < 2; ++c) { va[c] = *(const short8*)(gv + c*8); vb[c] = *(const short8*)(gv + Dd + c*8); }
            }
            __syncthreads();   // LDS tile ready

            // S = Q K^T
            f32x4 sc[4] = {};
            #pragma unroll
            for (int jk = 0; jk < 4; ++jk)
                #pragma unroll
                for (int ds = 0; ds < 4; ++ds) {
                    short8 kf = *(const short8*)&Ks[(jk*16 + l16)*136 + ds*32 + quad*8];
                    sc[jk] = __builtin_amdgcn_mfma_f32_16x16x32_bf16(qf[ds], kf, sc[jk], 0, 0, 0);
                }

            // causal mask only on the diagonal tile
            if (kt == qt) {
                const int qg = wave*16 + quad*4;       // local row base (same tile)
                #pragma unroll
                for (int jk = 0; jk < 4; ++jk) {
                    int kg = jk*16 + l16;
                    #pragma unroll
                    for (int r = 0; r < 4; ++r)
                        if (kg > qg + r) sc[jk][r] = -__builtin_inff();
                }
            }

            // online softmax: row max via 16-lane shuffle; sum kept as per-lane partial
            float alpha[4];
            #pragma unroll
            for (int r = 0; r < 4; ++r) {
                float m = fmaxf(fmaxf(sc[0][r], sc[1][r]), fmaxf(sc[2][r], sc[3][r]));
                #pragma unroll
                for (int off = 1; off < 16; off <<= 1)
                    m = fmaxf(m, __shfl_xor(m, off));
                float mn = fmaxf(m_i[r], m);
                alpha[r] = __expf(m_i[r] - mn);
                m_i[r] = mn;
                float s = 0.f;
                #pragma unroll
                for (int jk = 0; jk < 4; ++jk) {
                    float p = __expf(sc[jk][r] - mn);
                    sc[jk][r] = p;
                    s += p;
                }
                l_i[r] = l_i[r] * alpha[r] + s;   // per-lane partial; reduced in epilogue
            }

            // P (C/D layout) -> LDS -> A-operand layout (per-wave buffer, no barrier)
            #pragma unroll
            for (int jk = 0; jk < 4; ++jk)
                #pragma unroll
                for (int r = 0; r < 4; ++r)
                    Pw[wave][(quad*4 + r)*72 + jk*16 + l16] = (short)bf_rne(sc[jk][r]);

            #pragma unroll
            for (int dt = 0; dt < 8; ++dt)
                #pragma unroll
                for (int r = 0; r < 4; ++r)
                    o[dt][r] *= alpha[r];

            short8 pa[2];
            pa[0] = *(const short8*)&Pw[wave][l16*72 + quad*8];
            pa[1] = *(const short8*)&Pw[wave][l16*72 + 32 + quad*8];
            #pragma unroll
            for (int dt = 0; dt < 8; ++dt)
                #pragma unroll
                for (int kk = 0; kk < 2; ++kk) {
                    short8 vf = *(const short8*)&Vt[(dt*16 + l16)*72 + kk*32 + quad*8];
                    o[dt] = __builtin_amdgcn_mfma_f32_16x16x32_bf16(pa[kk], vf, o[dt], 0, 0, 0);
                }
        }

        // epilogue: reduce l across the 16 lanes holding each row, then store
        #pragma unroll
        for (int r = 0; r < 4; ++r) {
            float l = l_i[r];
            #pragma unroll
            for (int off = 1; off < 16; off <<= 1)
                l += __shfl_xor(l, off);
            float inv = 1.0f / l;
            int srow = qt*64 + wave*16 + quad*4 + r;
            size_t obase = ((size_t)b * Ss + srow) * Ee + h * Dd;
            #pragma unroll
            for (int dt = 0; dt < 8; ++dt)
                O[obase + dt*16 + l16] = (short)bf_rne(o[dt][r] * inv);
        }
    }
}

extern "C" void kernel_launch(void* const* d_in, const int* in_sizes, int n_in,
                              void* d_out, int out_size, void* d_ws, size_t ws_size,
                              hipStream_t stream) {
    const float* x_q  = (const float*)d_in[0];
    const float* x_kv = (const float*)d_in[1];
    const float* cosT = (const float*)d_in[2];
    const float* sinT = (const float*)d_in[3];
    const float* wq = (const float*)d_in[4];
    const float* bq = (const float*)d_in[5];
    const float* wk = (const float*)d_in[6];
    const float* bk = (const float*)d_in[7];
    const float* wv = (const float*)d_in[8];
    const float* bv = (const float*)d_in[9];
    const float* wo = (const float*)d_in[10];
    const float* bo = (const float*)d_in[11];

    size_t off = 0;
    auto alloc = [&](size_t bytes) {
        void* p = (char*)d_ws + off;
        off += (bytes + 255) & ~(size_t)255;
        return p;
    };
    const size_t nX = (size_t)Mrows * Ee;
    const size_t nW = (size_t)Ee * Ee;
    short* xq16  = (short*)alloc(nX * 2);
    short* xkv16 = (short*)alloc(nX * 2);
    short* wq16  = (short*)alloc(nW * 2);
    short* wk16  = (short*)alloc(nW * 2);
    short* wv16  = (short*)alloc(nW * 2);
    short* wo16  = (short*)alloc(nW * 2);
    short* Qr    = (short*)alloc(nX * 2);
    short* Kr    = (short*)alloc(nX * 2);
    short* Vb    = (short*)alloc(nX * 2);
    short* Ob    = (short*)alloc(nX * 2);

    cast4_kernel<<<(int)(nX/4 + 255)/256, 256, 0, stream>>>((const float4*)x_q,  (ushort4*)xq16,  (int)(nX/4));
    cast4_kernel<<<(int)(nX/4 + 255)/256, 256, 0, stream>>>((const float4*)x_kv, (ushort4*)xkv16, (int)(nX/4));
    cast4_kernel<<<(int)(nW/4 + 255)/256, 256, 0, stream>>>((const float4*)wq, (ushort4*)wq16, (int)(nW/4));
    cast4_kernel<<<(int)(nW/4 + 255)/256, 256, 0, stream>>>((const float4*)wk, (ushort4*)wk16, (int)(nW/4));
    cast4_kernel<<<(int)(nW/4 + 255)/256, 256, 0, stream>>>((const float4*)wv, (ushort4*)wv16, (int)(nW/4));
    cast4_kernel<<<(int)(nW/4 + 255)/256, 256, 0, stream>>>((const float4*)wo, (ushort4*)wo16, (int)(nW/4));

    dim3 ggrid(Mrows/128, Ee/128);
    gemm_bt<<<ggrid, 256, 0, stream>>>(xq16,  wq16, bq, nullptr, Qr, Mrows, Ee, Ee, 1);
    gemm_bt<<<ggrid, 256, 0, stream>>>(xkv16, wk16, bk, nullptr, Kr, Mrows, Ee, Ee, 1);
    gemm_bt<<<ggrid, 256, 0, stream>>>(xkv16, wv16, bv, nullptr, Vb, Mrows, Ee, Ee, 1);

    int rope_blocks = (Bb*Hh*Ss*64) / 256;
    rope_kernel<<<rope_blocks, 256, 0, stream>>>(Qr, cosT, sinT, 0.08838834764831845f);
    rope_kernel<<<rope_blocks, 256, 0, stream>>>(Kr, cosT, sinT, 1.0f);

    attn_kernel<<<dim3(16, Bb*Hh), 256, 0, stream>>>(Qr, Kr, Vb, Ob);

    gemm_bt<<<ggrid, 256, 0, stream>>>(Ob, wo16, bo, (float*)d_out, nullptr, Mrows, Ee, Ee, 0);
}